// Round 3
// baseline (3178.532 us; speedup 1.0000x reference)
//
#include <hip/hip_runtime.h>
#include <math.h>

typedef __attribute__((ext_vector_type(8))) short bf8;
typedef __attribute__((ext_vector_type(4))) float f32x4;
typedef __attribute__((ext_vector_type(4))) unsigned short us4;

// ---- LDS layout (bytes). All "planes" are bf16, XOR-swizzled byte^=((row&7)<<4).
#define XHI 0u          // x hi   [64][256] bf16, row stride 512B
#define XLO 32768u      // x lo
#define GHI 65536u      // rh / scratch hi [64][128], row stride 256B
#define GLO 81920u
#define H1HI 98304u     // h1 hi [64][128]
#define H1LO 114688u
#define SHI 131072u     // h2 hi [64][128]
#define SLO 147456u
#define LDS_TOTAL 163840

// ---- workspace layout (bytes)
#define WS_LFRAG 0                      // 2 x 1KB L fragments (hi, lo)
#define WS_W1G   4096                   // 16nt*12ks*2*1024 = 393216
#define WS_W1C   (WS_W1G + 393216)      // 8nt*12ks*2*1024 = 196608
#define WS_W2G   (WS_W1C + 196608)      // 16nt*8ks*2*1024 = 262144
#define WS_W2C   (WS_W2G + 262144)      // 8nt*8ks*2*1024 = 131072

__device__ __forceinline__ unsigned short f2bf(float x) {
    unsigned u = __float_as_uint(x);
    unsigned r = (u + 0x7fffu + ((u >> 16) & 1u)) >> 16;
    return (unsigned short)r;
}
__device__ __forceinline__ float bf2f(unsigned short h) {
    return __uint_as_float(((unsigned)h) << 16);
}
__device__ __forceinline__ f32x4 mfma16(bf8 a, bf8 b, f32x4 c) {
    return __builtin_amdgcn_mfma_f32_16x16x32_bf16(a, b, c, 0, 0, 0);
}

// one K=32 step of the main GEMM for one wave: 2 M-tiles x NNT N-tiles, split-bf16 (3 mfma)
template<int NNT>
__device__ __forceinline__ void kstep(const char* sm, unsigned hiOff, unsigned loOff, unsigned RS,
                                      unsigned s, const char* wb, unsigned NK, unsigned ks,
                                      unsigned t0, unsigned l, unsigned wi, f32x4* acc) {
    const unsigned lrow = l & 15u, lk = l >> 4;
    const unsigned kb = s * 64u + lk * 16u;
    const unsigned row0 = wi * 16u + lrow;
    const unsigned row1 = row0 + 32u;
    const unsigned sw = (lrow & 7u) << 4;
    const bf8 a0h = *(const bf8*)(sm + hiOff + row0 * RS + (kb ^ sw));
    const bf8 a0l = *(const bf8*)(sm + loOff + row0 * RS + (kb ^ sw));
    const bf8 a1h = *(const bf8*)(sm + hiOff + row1 * RS + (kb ^ sw));
    const bf8 a1l = *(const bf8*)(sm + loOff + row1 * RS + (kb ^ sw));
    // preload all B fragments first (gives the compiler a load cluster to pipeline)
    bf8 bh[NNT], bl[NNT];
#pragma unroll
    for (int i = 0; i < NNT; ++i) {
        unsigned nt = t0 + (unsigned)(i & 1) + (unsigned)(i >> 1) * 8u;
        const char* wp = wb + ((size_t)(nt * NK + ks) * 2048u) + l * 16u;
        bh[i] = *(const bf8*)(wp);
        bl[i] = *(const bf8*)(wp + 1024);
    }
#pragma unroll
    for (int i = 0; i < NNT; ++i) {
        f32x4 a = acc[i];
        a = mfma16(a0h, bh[i], a);
        a = mfma16(a0l, bh[i], a);
        a = mfma16(a0h, bl[i], a);
        acc[i] = a;
        f32x4 b = acc[NNT + i];
        b = mfma16(a1h, bh[i], b);
        b = mfma16(a1l, bh[i], b);
        b = mfma16(a1h, bl[i], b);
        acc[NNT + i] = b;
    }
}

// Laplacian aggregation on a C-fragment: D = L @ pre  (split bf16, 3 mfma, no lane moves)
__device__ __forceinline__ f32x4 agg3(bf8 Lhi, bf8 Llo, f32x4 p) {
    bf8 Bh = {0, 0, 0, 0, 0, 0, 0, 0};
    bf8 Bl = {0, 0, 0, 0, 0, 0, 0, 0};
#pragma unroll
    for (int q = 0; q < 4; ++q) {
        unsigned short h = f2bf(p[q]);
        Bh[q] = (short)h;
        Bl[q] = (short)f2bf(p[q] - bf2f(h));
    }
    f32x4 d = {0.f, 0.f, 0.f, 0.f};
    d = mfma16(Lhi, Bh, d);
    d = mfma16(Lhi, Bl, d);
    d = mfma16(Llo, Bh, d);
    return d;
}

__device__ __forceinline__ float plane_rd(const char* sm, unsigned hiOff, unsigned loOff,
                                          unsigned RS, unsigned row, unsigned col) {
    unsigned off = row * RS + ((col * 2u) ^ ((row & 7u) << 4));
    return bf2f(*(const unsigned short*)(sm + hiOff + off)) +
           bf2f(*(const unsigned short*)(sm + loOff + off));
}
__device__ __forceinline__ void plane_wr(char* sm, unsigned hiOff, unsigned loOff,
                                         unsigned RS, unsigned row, unsigned col, float v) {
    unsigned off = row * RS + ((col * 2u) ^ ((row & 7u) << 4));
    unsigned short h = f2bf(v);
    *(unsigned short*)(sm + hiOff + off) = h;
    *(unsigned short*)(sm + loOff + off) = f2bf(v - bf2f(h));
}

__device__ __forceinline__ float fast_sigm(float x) { return 1.0f / (1.0f + __expf(-x)); }
__device__ __forceinline__ float fast_tanh(float x) {
    x = fminf(fmaxf(x, -15.f), 15.f);
    float e = __expf(2.0f * x);
    return (e - 1.0f) / (e + 1.0f);
}

// ---------------- prep: Laplacian fragments ----------------
__global__ void tgcn_prep_L(const float* __restrict__ adj, char* __restrict__ ws) {
    __shared__ float d[16];
    __shared__ float Lm[16][16];
    int tid = threadIdx.x;
    if (tid < 16) {
        float rs = 1.0f;
        for (int j = 0; j < 16; ++j) rs += adj[tid * 16 + j];
        d[tid] = 1.0f / sqrtf(rs);
    }
    __syncthreads();
    if (tid < 256) {
        int i = tid >> 4, j = tid & 15;
        Lm[i][j] = (adj[j * 16 + i] + (i == j ? 1.0f : 0.0f)) * d[i] * d[j];
    }
    __syncthreads();
    if (tid < 128) {
        int h = tid >> 6, ll = tid & 63;
        int a = ll & 15, g = ll >> 4;
        bf8 f = {0, 0, 0, 0, 0, 0, 0, 0};
        // k-permutation: slot (lg, j<4) represents node 4*lg+j (consistent with agg3's B pack)
        for (int j = 0; j < 4; ++j) {
            float v = Lm[a][4 * g + j];
            unsigned short hi = f2bf(v);
            f[j] = (short)(h == 0 ? hi : f2bf(v - bf2f(hi)));
        }
        *(bf8*)(ws + WS_LFRAG + h * 1024 + ll * 16) = f;
    }
}

// ---------------- prep: weight fragment packing (hi/lo bf16) ----------------
__global__ void tgcn_prep_W(const float* __restrict__ w1g, const float* __restrict__ w1c,
                            const float* __restrict__ w2g, const float* __restrict__ w2c,
                            char* __restrict__ ws) {
    int gid = blockIdx.x * 256 + threadIdx.x;  // 480 frags * 64 lanes = 30720
    if (gid >= 30720) return;
    int fid = gid >> 6, l = gid & 63;
    const float* src; char* dst; int NK, N, nt, ks;
    if (fid < 192)      { src = w1g; dst = ws + WS_W1G; NK = 12; N = 256; nt = fid / 12; ks = fid % 12; }
    else if (fid < 288) { int f = fid - 192; src = w1c; dst = ws + WS_W1C; NK = 12; N = 128; nt = f / 12; ks = f % 12; }
    else if (fid < 416) { int f = fid - 288; src = w2g; dst = ws + WS_W2G; NK = 8;  N = 256; nt = f / 8;  ks = f % 8; }
    else                { int f = fid - 416; src = w2c; dst = ws + WS_W2C; NK = 8;  N = 128; nt = f / 8;  ks = f % 8; }
    int col = nt * 16 + (l & 15);
    int kbase = ks * 32 + (l >> 4) * 8;
    bf8 hi, lo;
#pragma unroll
    for (int j = 0; j < 8; ++j) {
        float v = src[(size_t)(kbase + j) * N + col];
        unsigned short h = f2bf(v);
        hi[j] = (short)h;
        lo[j] = (short)f2bf(v - bf2f(h));
    }
    char* base = dst + ((size_t)(nt * NK + ks) * 2048) + l * 16;
    *(bf8*)(base) = hi;
    *(bf8*)(base + 1024) = lo;
}

// ---------------- main fused kernel ----------------
__global__ __launch_bounds__(512, 1) void tgcn_main(
    const float* __restrict__ feat, const char* __restrict__ ws,
    const float* __restrict__ b1g, const float* __restrict__ b2g,
    const float* __restrict__ bng, const float* __restrict__ bnb,
    const float* __restrict__ bnm, const float* __restrict__ bnv,
    const float* __restrict__ fcw, const float* __restrict__ fcb,
    float* __restrict__ out) {
    extern __shared__ char sm[];
    const int tid = threadIdx.x;
    const int b0 = blockIdx.x * 4;
    const unsigned l = (unsigned)tid & 63u, w = (unsigned)tid >> 6;
    const unsigned wi = w & 1u, wj = w >> 1, t0 = 2u * wj;
    const unsigned lrow = l & 15u, lg = l >> 4;

    const bf8 Lhi = *(const bf8*)(ws + WS_LFRAG + l * 16u);
    const bf8 Llo = *(const bf8*)(ws + WS_LFRAG + 1024u + l * 16u);

    float bias1[4], bias2[4];
#pragma unroll
    for (int i = 0; i < 4; ++i) {
        unsigned nt = t0 + (unsigned)(i & 1) + (unsigned)(i >> 1) * 8u;
        bias1[i] = b1g[nt * 16u + lrow];
        bias2[i] = b2g[nt * 16u + lrow];
    }

    // zero h1 + h2 plane regions (65536 B starting at H1HI)
    {
        const f32x4 z = {0.f, 0.f, 0.f, 0.f};
#pragma unroll
        for (int p = 0; p < 8; ++p)
            *(f32x4*)(sm + H1HI + (unsigned)(tid + p * 512) * 16u) = z;
    }

    const char* wsW1G = ws + WS_W1G;
    const char* wsW1C = ws + WS_W1C;
    const char* wsW2G = ws + WS_W2G;
    const char* wsW2C = ws + WS_W2C;
    const f32x4 zf = {0.f, 0.f, 0.f, 0.f};

    for (int t = 0; t < 5; ++t) {
        // ---- stage x -> X hi/lo planes (swizzled); non-temporal so the 335 MB
        // feature stream doesn't evict the L2-resident weight fragments
        {
            f32x4 v[8];
#pragma unroll
            for (int p = 0; p < 8; ++p) {
                int e = tid + p * 512;
                int row = e >> 6, c4 = (e & 63) << 2;
                size_t gi = (((size_t)(b0 + (row >> 4)) * 5 + t) * 16 + (row & 15)) * 256 + c4;
                v[p] = __builtin_nontemporal_load((const f32x4*)(feat + gi));
            }
#pragma unroll
            for (int p = 0; p < 8; ++p) {
                int e = tid + p * 512;
                int row = e >> 6, c4 = (e & 63) << 2;
                unsigned off = (unsigned)row * 512u + (((unsigned)c4 * 2u) ^ (((unsigned)row & 7u) << 4));
                us4 hi, lo;
#pragma unroll
                for (int q = 0; q < 4; ++q) {
                    unsigned short h = f2bf(v[p][q]);
                    hi[q] = h;
                    lo[q] = f2bf(v[p][q] - bf2f(h));
                }
                *(us4*)(sm + XHI + off) = hi;
                *(us4*)(sm + XLO + off) = lo;
            }
        }
        __syncthreads();  // b1

        // ---- gates1: [x | h1] @ w1g, K=384, N=256
        f32x4 acc[8];
        f32x4 acc2[4];
        float u1[2][2][4];
#pragma unroll
        for (int i = 0; i < 8; ++i) acc[i] = zf;
#pragma unroll
        for (int ks = 0; ks < 12; ++ks) {
            if (ks < 8) kstep<4>(sm, XHI, XLO, 512u, (unsigned)ks, wsW1G, 12u, (unsigned)ks, t0, l, wi, acc);
            else        kstep<4>(sm, H1HI, H1LO, 256u, (unsigned)(ks - 8), wsW1G, 12u, (unsigned)ks, t0, l, wi, acc);
        }
#pragma unroll
        for (int m2 = 0; m2 < 2; ++m2) {
#pragma unroll
            for (int i = 0; i < 4; ++i) {
                f32x4 g = agg3(Lhi, Llo, acc[m2 * 4 + i]);
                unsigned nt = t0 + (unsigned)(i & 1) + (unsigned)(i >> 1) * 8u;
                unsigned colg = nt * 16u + lrow;
#pragma unroll
                for (int q = 0; q < 4; ++q) {
                    float s = fast_sigm(g[q] + bias1[i]);
                    unsigned row = (wi + 2u * m2) * 16u + lg * 4u + q;
                    if (i < 2) {  // r tile -> rh = r*h1 into G planes
                        float h1v = plane_rd(sm, H1HI, H1LO, 256u, row, colg);
                        plane_wr(sm, GHI, GLO, 256u, row, colg, s * h1v);
                    } else {      // u tile -> registers
                        u1[m2][i - 2][q] = s;
                    }
                }
            }
        }
        __syncthreads();  // b2

        // ---- cand1: [x | rh] @ w1c, K=384, N=128; h1 update
#pragma unroll
        for (int i = 0; i < 4; ++i) acc2[i] = zf;
#pragma unroll
        for (int ks = 0; ks < 12; ++ks) {
            if (ks < 8) kstep<2>(sm, XHI, XLO, 512u, (unsigned)ks, wsW1C, 12u, (unsigned)ks, t0, l, wi, acc2);
            else        kstep<2>(sm, GHI, GLO, 256u, (unsigned)(ks - 8), wsW1C, 12u, (unsigned)ks, t0, l, wi, acc2);
        }
#pragma unroll
        for (int m2 = 0; m2 < 2; ++m2) {
#pragma unroll
            for (int i = 0; i < 2; ++i) {
                f32x4 c = agg3(Lhi, Llo, acc2[m2 * 2 + i]);
                unsigned col = (t0 + (unsigned)i) * 16u + lrow;
#pragma unroll
                for (int q = 0; q < 4; ++q) {
                    float cv = fast_tanh(c[q]);
                    float u = u1[m2][i][q];
                    unsigned row = (wi + 2u * m2) * 16u + lg * 4u + q;
                    float hv = plane_rd(sm, H1HI, H1LO, 256u, row, col);
                    plane_wr(sm, H1HI, H1LO, 256u, row, col, u * hv + (1.0f - u) * cv);
                }
            }
        }
        __syncthreads();  // b3

        // ---- gates2: [h1 | h2] @ w2g, K=256, N=256
#pragma unroll
        for (int i = 0; i < 8; ++i) acc[i] = zf;
#pragma unroll
        for (int ks = 0; ks < 8; ++ks) {
            if (ks < 4) kstep<4>(sm, H1HI, H1LO, 256u, (unsigned)ks, wsW2G, 8u, (unsigned)ks, t0, l, wi, acc);
            else        kstep<4>(sm, SHI, SLO, 256u, (unsigned)(ks - 4), wsW2G, 8u, (unsigned)ks, t0, l, wi, acc);
        }
#pragma unroll
        for (int m2 = 0; m2 < 2; ++m2) {
#pragma unroll
            for (int i = 0; i < 4; ++i) {
                f32x4 g = agg3(Lhi, Llo, acc[m2 * 4 + i]);
                unsigned nt = t0 + (unsigned)(i & 1) + (unsigned)(i >> 1) * 8u;
                unsigned colg = nt * 16u + lrow;
#pragma unroll
                for (int q = 0; q < 4; ++q) {
                    float s = fast_sigm(g[q] + bias2[i]);
                    unsigned row = (wi + 2u * m2) * 16u + lg * 4u + q;
                    if (i < 2) {  // rh2 = r2*h2 into G planes
                        float h2v = plane_rd(sm, SHI, SLO, 256u, row, colg);
                        plane_wr(sm, GHI, GLO, 256u, row, colg, s * h2v);
                    } else {
                        u1[m2][i - 2][q] = s;
                    }
                }
            }
        }
        __syncthreads();  // b4

        // ---- cand2: [h1 | rh2] @ w2c, K=256, N=128; h2 update
#pragma unroll
        for (int i = 0; i < 4; ++i) acc2[i] = zf;
#pragma unroll
        for (int ks = 0; ks < 8; ++ks) {
            if (ks < 4) kstep<2>(sm, H1HI, H1LO, 256u, (unsigned)ks, wsW2C, 8u, (unsigned)ks, t0, l, wi, acc2);
            else        kstep<2>(sm, GHI, GLO, 256u, (unsigned)(ks - 4), wsW2C, 8u, (unsigned)ks, t0, l, wi, acc2);
        }
#pragma unroll
        for (int m2 = 0; m2 < 2; ++m2) {
#pragma unroll
            for (int i = 0; i < 2; ++i) {
                f32x4 c = agg3(Lhi, Llo, acc2[m2 * 2 + i]);
                unsigned col = (t0 + (unsigned)i) * 16u + lrow;
#pragma unroll
                for (int q = 0; q < 4; ++q) {
                    float cv = fast_tanh(c[q]);
                    float u = u1[m2][i][q];
                    unsigned row = (wi + 2u * m2) * 16u + lg * 4u + q;
                    float hv = plane_rd(sm, SHI, SLO, 256u, row, col);
                    plane_wr(sm, SHI, SLO, 256u, row, col, u * hv + (1.0f - u) * cv);
                }
            }
        }
        __syncthreads();  // b5
    }

    // ---- head: BN -> ReLU -> FC(2048->2) from h2 (S planes)
    {
        int row = tid >> 3, cb = tid & 7;
        int a = row & 15;
        unsigned c0 = (unsigned)cb * 16u;
        unsigned sw = ((unsigned)row & 7u) << 4;
        unsigned base = (unsigned)row * 256u;
        unsigned o0 = base + ((c0 * 2u) ^ sw);
        unsigned o1 = base + ((c0 * 2u + 16u) ^ sw);
        bf8 hA = *(const bf8*)(sm + SHI + o0);
        bf8 hB = *(const bf8*)(sm + SHI + o1);
        bf8 lA = *(const bf8*)(sm + SLO + o0);
        bf8 lB = *(const bf8*)(sm + SLO + o1);
        int k2 = a * 128 + (int)c0;
        float p0 = 0.f, p1 = 0.f;
#pragma unroll
        for (int j = 0; j < 16; ++j) {
            unsigned short hh = (unsigned short)(j < 8 ? hA[j] : hB[j - 8]);
            unsigned short ll = (unsigned short)(j < 8 ? lA[j] : lB[j - 8]);
            float v = bf2f(hh) + bf2f(ll);
            int k = k2 + j;
            float x = bng[k] * (v - bnm[k]) * rsqrtf(bnv[k] + 1e-5f) + bnb[k];
            x = fmaxf(x, 0.f);
            p0 += x * fcw[2 * k];
            p1 += x * fcw[2 * k + 1];
        }
        p0 += __shfl_down(p0, 4, 8); p0 += __shfl_down(p0, 2, 8); p0 += __shfl_down(p0, 1, 8);
        p1 += __shfl_down(p1, 4, 8); p1 += __shfl_down(p1, 2, 8); p1 += __shfl_down(p1, 1, 8);
        if ((tid & 7) == 0) {
            ((float*)(sm + GHI))[row * 2] = p0;
            ((float*)(sm + GHI))[row * 2 + 1] = p1;
        }
        __syncthreads();
        if (tid < 8) {
            int b = tid >> 1, o = tid & 1;
            float s = fcb[o];
#pragma unroll
            for (int aa = 0; aa < 16; ++aa) s += ((const float*)(sm + GHI))[(b * 16 + aa) * 2 + o];
            out[(size_t)(b0 + b) * 2 + o] = s;
        }
    }
}

extern "C" void kernel_launch(void* const* d_in, const int* in_sizes, int n_in,
                              void* d_out, int out_size, void* d_ws, size_t ws_size,
                              hipStream_t stream) {
    const float* feat = (const float*)d_in[0];
    const float* adj  = (const float*)d_in[1];
    const float* w1g  = (const float*)d_in[2];
    const float* b1g  = (const float*)d_in[3];
    const float* w1c  = (const float*)d_in[4];
    const float* w2g  = (const float*)d_in[5];
    const float* b2g  = (const float*)d_in[6];
    const float* w2c  = (const float*)d_in[7];
    const float* bng  = (const float*)d_in[8];
    const float* bnb  = (const float*)d_in[9];
    const float* bnm  = (const float*)d_in[10];
    const float* bnv  = (const float*)d_in[11];
    const float* fcw  = (const float*)d_in[12];
    const float* fcb  = (const float*)d_in[13];
    float* out = (float*)d_out;
    char* ws = (char*)d_ws;

    int B = in_sizes[0] / (5 * 16 * 256);  // 4096

    hipFuncSetAttribute((const void*)tgcn_main,
                        hipFuncAttributeMaxDynamicSharedMemorySize, LDS_TOTAL);

    tgcn_prep_L<<<1, 256, 0, stream>>>(adj, ws);
    tgcn_prep_W<<<120, 256, 0, stream>>>(w1g, w1c, w2g, w2c, ws);
    tgcn_main<<<B / 4, 512, LDS_TOTAL, stream>>>(feat, ws, b1g, b2g,
                                                 bng, bnb, bnm, bnv, fcw, fcb, out);
}

// Round 4
// 638.998 us; speedup vs baseline: 4.9742x; 4.9742x over previous
//
#include <hip/hip_runtime.h>
#include <math.h>

typedef __attribute__((ext_vector_type(8))) short bf8;
typedef __attribute__((ext_vector_type(4))) float f32x4;
typedef __attribute__((ext_vector_type(4))) unsigned short us4;

// ---- LDS layout (bytes). All "planes" are bf16, XOR-swizzled byte^=((row&7)<<4).
#define XHI 0u          // x hi   [64][256] bf16, row stride 512B
#define XLO 32768u      // x lo
#define GHI 65536u      // rh / scratch hi [64][128], row stride 256B
#define GLO 81920u
#define H1HI 98304u     // h1 hi [64][128]
#define H1LO 114688u
#define SHI 131072u     // h2 hi [64][128]
#define SLO 147456u
#define LDS_TOTAL 163840

// ---- workspace layout (bytes)
#define WS_LFRAG 0                      // 2 x 1KB L fragments (hi, lo)
#define WS_W1G   4096                   // 16nt*12ks*2*1024 = 393216
#define WS_W1C   (WS_W1G + 393216)      // 8nt*12ks*2*1024 = 196608
#define WS_W2G   (WS_W1C + 196608)      // 16nt*8ks*2*1024 = 262144
#define WS_W2C   (WS_W2G + 262144)      // 8nt*8ks*2*1024 = 131072

__device__ __forceinline__ unsigned short f2bf(float x) {
    unsigned u = __float_as_uint(x);
    unsigned r = (u + 0x7fffu + ((u >> 16) & 1u)) >> 16;
    return (unsigned short)r;
}
__device__ __forceinline__ float bf2f(unsigned short h) {
    return __uint_as_float(((unsigned)h) << 16);
}
__device__ __forceinline__ f32x4 mfma16(bf8 a, bf8 b, f32x4 c) {
    return __builtin_amdgcn_mfma_f32_16x16x32_bf16(a, b, c, 0, 0, 0);
}

// One K-segment of a GEMM pass: 2 M-tiles x 2 N-tiles (acc[4]), split-bf16 (3 mfma each).
// acc[2*i + m2] = fragment (m-tile m2, n-tile {ntA,ntB}[i]).
// Low register pressure by design: acc(16) + 4 A-frags(16) + 2 B-frags(8) live.
template<int KS>
__device__ __forceinline__ void gemmSeg(const char* sm, unsigned hiO, unsigned loO, unsigned rs,
                                        const char* wb, unsigned NK, unsigned ksBase,
                                        unsigned ntA, unsigned ntB,
                                        unsigned l, unsigned wi, f32x4* acc) {
    const unsigned lrow = l & 15u, lk = l >> 4;
    const unsigned row0 = wi * 16u + lrow, row1 = row0 + 32u;
    const unsigned sw = (lrow & 7u) << 4;
    const char* pA0h = sm + hiO + row0 * rs;
    const char* pA0l = sm + loO + row0 * rs;
    const char* pA1h = sm + hiO + row1 * rs;
    const char* pA1l = sm + loO + row1 * rs;
    const char* wpA = wb + ((size_t)(ntA * NK + ksBase) * 2048u) + l * 16u;
    const char* wpB = wb + ((size_t)(ntB * NK + ksBase) * 2048u) + l * 16u;
#pragma unroll 2
    for (int ks = 0; ks < KS; ++ks) {
        const unsigned kb = ((unsigned)ks * 64u + lk * 16u) ^ sw;
        const bf8 a0h = *(const bf8*)(pA0h + kb);
        const bf8 a0l = *(const bf8*)(pA0l + kb);
        const bf8 a1h = *(const bf8*)(pA1h + kb);
        const bf8 a1l = *(const bf8*)(pA1l + kb);
        {
            const bf8 bh = *(const bf8*)(wpA + (size_t)ks * 2048u);
            const bf8 bl = *(const bf8*)(wpA + (size_t)ks * 2048u + 1024u);
            acc[0] = mfma16(a0l, bh, mfma16(a0h, bl, mfma16(a0h, bh, acc[0])));
            acc[1] = mfma16(a1l, bh, mfma16(a1h, bl, mfma16(a1h, bh, acc[1])));
        }
        {
            const bf8 bh = *(const bf8*)(wpB + (size_t)ks * 2048u);
            const bf8 bl = *(const bf8*)(wpB + (size_t)ks * 2048u + 1024u);
            acc[2] = mfma16(a0l, bh, mfma16(a0h, bl, mfma16(a0h, bh, acc[2])));
            acc[3] = mfma16(a1l, bh, mfma16(a1h, bl, mfma16(a1h, bh, acc[3])));
        }
    }
}

// Laplacian aggregation on a C-fragment: D = L @ pre  (split bf16, 3 mfma, no lane moves)
__device__ __forceinline__ f32x4 agg3(bf8 Lhi, bf8 Llo, f32x4 p) {
    bf8 Bh = {0, 0, 0, 0, 0, 0, 0, 0};
    bf8 Bl = {0, 0, 0, 0, 0, 0, 0, 0};
#pragma unroll
    for (int q = 0; q < 4; ++q) {
        unsigned short h = f2bf(p[q]);
        Bh[q] = (short)h;
        Bl[q] = (short)f2bf(p[q] - bf2f(h));
    }
    f32x4 d = {0.f, 0.f, 0.f, 0.f};
    d = mfma16(Lhi, Bh, d);
    d = mfma16(Lhi, Bl, d);
    d = mfma16(Llo, Bh, d);
    return d;
}

__device__ __forceinline__ float plane_rd(const char* sm, unsigned hiOff, unsigned loOff,
                                          unsigned RS, unsigned row, unsigned col) {
    unsigned off = row * RS + ((col * 2u) ^ ((row & 7u) << 4));
    return bf2f(*(const unsigned short*)(sm + hiOff + off)) +
           bf2f(*(const unsigned short*)(sm + loOff + off));
}
__device__ __forceinline__ void plane_wr(char* sm, unsigned hiOff, unsigned loOff,
                                         unsigned RS, unsigned row, unsigned col, float v) {
    unsigned off = row * RS + ((col * 2u) ^ ((row & 7u) << 4));
    unsigned short h = f2bf(v);
    *(unsigned short*)(sm + hiOff + off) = h;
    *(unsigned short*)(sm + loOff + off) = f2bf(v - bf2f(h));
}

__device__ __forceinline__ float fast_sigm(float x) { return 1.0f / (1.0f + __expf(-x)); }
__device__ __forceinline__ float fast_tanh(float x) {
    x = fminf(fmaxf(x, -15.f), 15.f);
    float e = __expf(2.0f * x);
    return (e - 1.0f) / (e + 1.0f);
}

// ---------------- prep: Laplacian fragments ----------------
__global__ void tgcn_prep_L(const float* __restrict__ adj, char* __restrict__ ws) {
    __shared__ float d[16];
    __shared__ float Lm[16][16];
    int tid = threadIdx.x;
    if (tid < 16) {
        float rs = 1.0f;
        for (int j = 0; j < 16; ++j) rs += adj[tid * 16 + j];
        d[tid] = 1.0f / sqrtf(rs);
    }
    __syncthreads();
    if (tid < 256) {
        int i = tid >> 4, j = tid & 15;
        Lm[i][j] = (adj[j * 16 + i] + (i == j ? 1.0f : 0.0f)) * d[i] * d[j];
    }
    __syncthreads();
    if (tid < 128) {
        int h = tid >> 6, ll = tid & 63;
        int a = ll & 15, g = ll >> 4;
        bf8 f = {0, 0, 0, 0, 0, 0, 0, 0};
        // k-permutation: slot (lg, j<4) represents node 4*lg+j (consistent with agg3's B pack)
        for (int j = 0; j < 4; ++j) {
            float v = Lm[a][4 * g + j];
            unsigned short hi = f2bf(v);
            f[j] = (short)(h == 0 ? hi : f2bf(v - bf2f(hi)));
        }
        *(bf8*)(ws + WS_LFRAG + h * 1024 + ll * 16) = f;
    }
}

// ---------------- prep: weight fragment packing (hi/lo bf16) ----------------
__global__ void tgcn_prep_W(const float* __restrict__ w1g, const float* __restrict__ w1c,
                            const float* __restrict__ w2g, const float* __restrict__ w2c,
                            char* __restrict__ ws) {
    int gid = blockIdx.x * 256 + threadIdx.x;  // 480 frags * 64 lanes = 30720
    if (gid >= 30720) return;
    int fid = gid >> 6, l = gid & 63;
    const float* src; char* dst; int NK, N, nt, ks;
    if (fid < 192)      { src = w1g; dst = ws + WS_W1G; NK = 12; N = 256; nt = fid / 12; ks = fid % 12; }
    else if (fid < 288) { int f = fid - 192; src = w1c; dst = ws + WS_W1C; NK = 12; N = 128; nt = f / 12; ks = f % 12; }
    else if (fid < 416) { int f = fid - 288; src = w2g; dst = ws + WS_W2G; NK = 8;  N = 256; nt = f / 8;  ks = f % 8; }
    else                { int f = fid - 416; src = w2c; dst = ws + WS_W2C; NK = 8;  N = 128; nt = f / 8;  ks = f % 8; }
    int col = nt * 16 + (l & 15);
    int kbase = ks * 32 + (l >> 4) * 8;
    bf8 hi, lo;
#pragma unroll
    for (int j = 0; j < 8; ++j) {
        float v = src[(size_t)(kbase + j) * N + col];
        unsigned short h = f2bf(v);
        hi[j] = (short)h;
        lo[j] = (short)f2bf(v - bf2f(h));
    }
    char* base = dst + ((size_t)(nt * NK + ks) * 2048) + l * 16;
    *(bf8*)(base) = hi;
    *(bf8*)(base + 1024) = lo;
}

// ---------------- main fused kernel ----------------
// amdgpu_waves_per_eu(2,2): LDS (160KB, dynamic -> invisible to the allocator) caps us at
// 1 block/CU = 2 waves/SIMD anyway; tell the allocator so it uses the full 256-VGPR budget
// instead of targeting 4 waves/SIMD and spilling to scratch.
__global__ __launch_bounds__(512)
__attribute__((amdgpu_waves_per_eu(2, 2)))
void tgcn_main(
    const float* __restrict__ feat, const char* __restrict__ ws,
    const float* __restrict__ b1g, const float* __restrict__ b2g,
    const float* __restrict__ bng, const float* __restrict__ bnb,
    const float* __restrict__ bnm, const float* __restrict__ bnv,
    const float* __restrict__ fcw, const float* __restrict__ fcb,
    float* __restrict__ out) {
    extern __shared__ char sm[];
    const int tid = threadIdx.x;
    const int b0 = blockIdx.x * 4;
    const unsigned l = (unsigned)tid & 63u, w = (unsigned)tid >> 6;
    const unsigned wi = w & 1u, wj = w >> 1, t0 = 2u * wj;
    const unsigned lrow = l & 15u, lg = l >> 4;

    const bf8 Lhi = *(const bf8*)(ws + WS_LFRAG + l * 16u);
    const bf8 Llo = *(const bf8*)(ws + WS_LFRAG + 1024u + l * 16u);

    float bias1[4], bias2[4];   // [0..1]=r tiles (nt=t0+i), [2..3]=u tiles (nt=t0+8+i)
#pragma unroll
    for (int i = 0; i < 4; ++i) {
        unsigned nt = t0 + (unsigned)(i & 1) + (unsigned)(i >> 1) * 8u;
        bias1[i] = b1g[nt * 16u + lrow];
        bias2[i] = b2g[nt * 16u + lrow];
    }

    // zero h1 + h2 plane regions (65536 B starting at H1HI)
    {
        const f32x4 z = {0.f, 0.f, 0.f, 0.f};
#pragma unroll
        for (int p = 0; p < 8; ++p)
            *(f32x4*)(sm + H1HI + (unsigned)(tid + p * 512) * 16u) = z;
    }

    const char* wsW1G = ws + WS_W1G;
    const char* wsW1C = ws + WS_W1C;
    const char* wsW2G = ws + WS_W2G;
    const char* wsW2C = ws + WS_W2C;
    const f32x4 zf = {0.f, 0.f, 0.f, 0.f};

    for (int t = 0; t < 5; ++t) {
        // ---- stage x -> X hi/lo planes (swizzled); non-temporal (stream, read once)
        {
            f32x4 v[8];
#pragma unroll
            for (int p = 0; p < 8; ++p) {
                int e = tid + p * 512;
                int row = e >> 6, c4 = (e & 63) << 2;
                size_t gi = (((size_t)(b0 + (row >> 4)) * 5 + t) * 16 + (row & 15)) * 256 + c4;
                v[p] = __builtin_nontemporal_load((const f32x4*)(feat + gi));
            }
#pragma unroll
            for (int p = 0; p < 8; ++p) {
                int e = tid + p * 512;
                int row = e >> 6, c4 = (e & 63) << 2;
                unsigned off = (unsigned)row * 512u + (((unsigned)c4 * 2u) ^ (((unsigned)row & 7u) << 4));
                us4 hi, lo;
#pragma unroll
                for (int q = 0; q < 4; ++q) {
                    unsigned short h = f2bf(v[p][q]);
                    hi[q] = h;
                    lo[q] = f2bf(v[p][q] - bf2f(h));
                }
                *(us4*)(sm + XHI + off) = hi;
                *(us4*)(sm + XLO + off) = lo;
            }
        }
        __syncthreads();  // b1

        float u1[2][2][4];

        // ---- gates1 r-half: [x | h1] @ w1g[:, r-cols], K=384 -> rh into G planes
        {
            f32x4 acc[4] = {zf, zf, zf, zf};
            gemmSeg<8>(sm, XHI, XLO, 512u, wsW1G, 12u, 0u, t0, t0 + 1u, l, wi, acc);
            gemmSeg<4>(sm, H1HI, H1LO, 256u, wsW1G, 12u, 8u, t0, t0 + 1u, l, wi, acc);
#pragma unroll
            for (int m2 = 0; m2 < 2; ++m2) {
#pragma unroll
                for (int i = 0; i < 2; ++i) {
                    f32x4 g = agg3(Lhi, Llo, acc[2 * i + m2]);
                    unsigned colg = (t0 + (unsigned)i) * 16u + lrow;
#pragma unroll
                    for (int q = 0; q < 4; ++q) {
                        float s = fast_sigm(g[q] + bias1[i]);
                        unsigned row = (wi + 2u * m2) * 16u + lg * 4u + q;
                        float h1v = plane_rd(sm, H1HI, H1LO, 256u, row, colg);
                        plane_wr(sm, GHI, GLO, 256u, row, colg, s * h1v);
                    }
                }
            }
        }
        // ---- gates1 u-half: u tiles -> registers
        {
            f32x4 acc[4] = {zf, zf, zf, zf};
            gemmSeg<8>(sm, XHI, XLO, 512u, wsW1G, 12u, 0u, t0 + 8u, t0 + 9u, l, wi, acc);
            gemmSeg<4>(sm, H1HI, H1LO, 256u, wsW1G, 12u, 8u, t0 + 8u, t0 + 9u, l, wi, acc);
#pragma unroll
            for (int m2 = 0; m2 < 2; ++m2) {
#pragma unroll
                for (int i = 0; i < 2; ++i) {
                    f32x4 g = agg3(Lhi, Llo, acc[2 * i + m2]);
#pragma unroll
                    for (int q = 0; q < 4; ++q)
                        u1[m2][i][q] = fast_sigm(g[q] + bias1[2 + i]);
                }
            }
        }
        __syncthreads();  // b2

        // ---- cand1: [x | rh] @ w1c, K=384; h1 = u*h1 + (1-u)*tanh(c)
        {
            f32x4 acc[4] = {zf, zf, zf, zf};
            gemmSeg<8>(sm, XHI, XLO, 512u, wsW1C, 12u, 0u, t0, t0 + 1u, l, wi, acc);
            gemmSeg<4>(sm, GHI, GLO, 256u, wsW1C, 12u, 8u, t0, t0 + 1u, l, wi, acc);
#pragma unroll
            for (int m2 = 0; m2 < 2; ++m2) {
#pragma unroll
                for (int i = 0; i < 2; ++i) {
                    f32x4 c = agg3(Lhi, Llo, acc[2 * i + m2]);
                    unsigned col = (t0 + (unsigned)i) * 16u + lrow;
#pragma unroll
                    for (int q = 0; q < 4; ++q) {
                        float cv = fast_tanh(c[q]);
                        float u = u1[m2][i][q];
                        unsigned row = (wi + 2u * m2) * 16u + lg * 4u + q;
                        float hv = plane_rd(sm, H1HI, H1LO, 256u, row, col);
                        plane_wr(sm, H1HI, H1LO, 256u, row, col, u * hv + (1.0f - u) * cv);
                    }
                }
            }
        }
        __syncthreads();  // b3

        // ---- gates2 r-half: [h1 | h2] @ w2g, K=256 -> rh2 into G
        {
            f32x4 acc[4] = {zf, zf, zf, zf};
            gemmSeg<4>(sm, H1HI, H1LO, 256u, wsW2G, 8u, 0u, t0, t0 + 1u, l, wi, acc);
            gemmSeg<4>(sm, SHI, SLO, 256u, wsW2G, 8u, 4u, t0, t0 + 1u, l, wi, acc);
#pragma unroll
            for (int m2 = 0; m2 < 2; ++m2) {
#pragma unroll
                for (int i = 0; i < 2; ++i) {
                    f32x4 g = agg3(Lhi, Llo, acc[2 * i + m2]);
                    unsigned colg = (t0 + (unsigned)i) * 16u + lrow;
#pragma unroll
                    for (int q = 0; q < 4; ++q) {
                        float s = fast_sigm(g[q] + bias2[i]);
                        unsigned row = (wi + 2u * m2) * 16u + lg * 4u + q;
                        float h2v = plane_rd(sm, SHI, SLO, 256u, row, colg);
                        plane_wr(sm, GHI, GLO, 256u, row, colg, s * h2v);
                    }
                }
            }
        }
        // ---- gates2 u-half
        {
            f32x4 acc[4] = {zf, zf, zf, zf};
            gemmSeg<4>(sm, H1HI, H1LO, 256u, wsW2G, 8u, 0u, t0 + 8u, t0 + 9u, l, wi, acc);
            gemmSeg<4>(sm, SHI, SLO, 256u, wsW2G, 8u, 4u, t0 + 8u, t0 + 9u, l, wi, acc);
#pragma unroll
            for (int m2 = 0; m2 < 2; ++m2) {
#pragma unroll
                for (int i = 0; i < 2; ++i) {
                    f32x4 g = agg3(Lhi, Llo, acc[2 * i + m2]);
#pragma unroll
                    for (int q = 0; q < 4; ++q)
                        u1[m2][i][q] = fast_sigm(g[q] + bias2[2 + i]);
                }
            }
        }
        __syncthreads();  // b4

        // ---- cand2: [h1 | rh2] @ w2c, K=256; h2 update
        {
            f32x4 acc[4] = {zf, zf, zf, zf};
            gemmSeg<4>(sm, H1HI, H1LO, 256u, wsW2C, 8u, 0u, t0, t0 + 1u, l, wi, acc);
            gemmSeg<4>(sm, GHI, GLO, 256u, wsW2C, 8u, 4u, t0, t0 + 1u, l, wi, acc);
#pragma unroll
            for (int m2 = 0; m2 < 2; ++m2) {
#pragma unroll
                for (int i = 0; i < 2; ++i) {
                    f32x4 c = agg3(Lhi, Llo, acc[2 * i + m2]);
                    unsigned col = (t0 + (unsigned)i) * 16u + lrow;
#pragma unroll
                    for (int q = 0; q < 4; ++q) {
                        float cv = fast_tanh(c[q]);
                        float u = u1[m2][i][q];
                        unsigned row = (wi + 2u * m2) * 16u + lg * 4u + q;
                        float hv = plane_rd(sm, SHI, SLO, 256u, row, col);
                        plane_wr(sm, SHI, SLO, 256u, row, col, u * hv + (1.0f - u) * cv);
                    }
                }
            }
        }
        __syncthreads();  // b5
    }

    // ---- head: BN -> ReLU -> FC(2048->2) from h2 (S planes)
    {
        int row = tid >> 3, cb = tid & 7;
        int a = row & 15;
        unsigned c0 = (unsigned)cb * 16u;
        unsigned sw = ((unsigned)row & 7u) << 4;
        unsigned base = (unsigned)row * 256u;
        unsigned o0 = base + ((c0 * 2u) ^ sw);
        unsigned o1 = base + ((c0 * 2u + 16u) ^ sw);
        bf8 hA = *(const bf8*)(sm + SHI + o0);
        bf8 hB = *(const bf8*)(sm + SHI + o1);
        bf8 lA = *(const bf8*)(sm + SLO + o0);
        bf8 lB = *(const bf8*)(sm + SLO + o1);
        int k2 = a * 128 + (int)c0;
        float p0 = 0.f, p1 = 0.f;
#pragma unroll
        for (int j = 0; j < 16; ++j) {
            unsigned short hh = (unsigned short)(j < 8 ? hA[j] : hB[j - 8]);
            unsigned short ll = (unsigned short)(j < 8 ? lA[j] : lB[j - 8]);
            float v = bf2f(hh) + bf2f(ll);
            int k = k2 + j;
            float x = bng[k] * (v - bnm[k]) * rsqrtf(bnv[k] + 1e-5f) + bnb[k];
            x = fmaxf(x, 0.f);
            p0 += x * fcw[2 * k];
            p1 += x * fcw[2 * k + 1];
        }
        p0 += __shfl_down(p0, 4, 8); p0 += __shfl_down(p0, 2, 8); p0 += __shfl_down(p0, 1, 8);
        p1 += __shfl_down(p1, 4, 8); p1 += __shfl_down(p1, 2, 8); p1 += __shfl_down(p1, 1, 8);
        if ((tid & 7) == 0) {
            ((float*)(sm + GHI))[row * 2] = p0;
            ((float*)(sm + GHI))[row * 2 + 1] = p1;
        }
        __syncthreads();
        if (tid < 8) {
            int b = tid >> 1, o = tid & 1;
            float s = fcb[o];
#pragma unroll
            for (int aa = 0; aa < 16; ++aa) s += ((const float*)(sm + GHI))[(b * 16 + aa) * 2 + o];
            out[(size_t)(b0 + b) * 2 + o] = s;
        }
    }
}

extern "C" void kernel_launch(void* const* d_in, const int* in_sizes, int n_in,
                              void* d_out, int out_size, void* d_ws, size_t ws_size,
                              hipStream_t stream) {
    const float* feat = (const float*)d_in[0];
    const float* adj  = (const float*)d_in[1];
    const float* w1g  = (const float*)d_in[2];
    const float* b1g  = (const float*)d_in[3];
    const float* w1c  = (const float*)d_in[4];
    const float* w2g  = (const float*)d_in[5];
    const float* b2g  = (const float*)d_in[6];
    const float* w2c  = (const float*)d_in[7];
    const float* bng  = (const float*)d_in[8];
    const float* bnb  = (const float*)d_in[9];
    const float* bnm  = (const float*)d_in[10];
    const float* bnv  = (const float*)d_in[11];
    const float* fcw  = (const float*)d_in[12];
    const float* fcb  = (const float*)d_in[13];
    float* out = (float*)d_out;
    char* ws = (char*)d_ws;

    int B = in_sizes[0] / (5 * 16 * 256);  // 4096

    hipFuncSetAttribute((const void*)tgcn_main,
                        hipFuncAttributeMaxDynamicSharedMemorySize, LDS_TOTAL);

    tgcn_prep_L<<<1, 256, 0, stream>>>(adj, ws);
    tgcn_prep_W<<<120, 256, 0, stream>>>(w1g, w1c, w2g, w2c, ws);
    tgcn_main<<<B / 4, 512, LDS_TOTAL, stream>>>(feat, ws, b1g, b2g,
                                                 bng, bnb, bnm, bnv, fcw, fcb, out);
}